// Round 6
// baseline (681.842 us; speedup 1.0000x reference)
//
#include <hip/hip_runtime.h>
#include <math.h>

#define HIDDEN 1024
#define SEQ    4096
#define BATCH  4

typedef _Float16 f16x8 __attribute__((ext_vector_type(8)));
typedef float    floatx4 __attribute__((ext_vector_type(4)));

// async 16B global->LDS copy (m97: width=16 emits global_load_lds_dwordx4)
__device__ inline void gld16(const void* g, void* l) {
    __builtin_amdgcn_global_load_lds(
        (const __attribute__((address_space(1))) unsigned int*)g,
        (__attribute__((address_space(3))) unsigned int*)l, 16, 0, 0);
}

// ===========================================================================
// 128x128-tile kernel, 256 thr = 4 waves (2x2), wave tile 64x64.
// ~152 regs/thread -> 3 blocks/CU co-resident (QK needs this latency hiding).
// MODE 5: fused QKV projection. grid (24,128,1). A=Xh [16384,1024].
//         which = col0>>10 picks Wq/Wk/Wv; which<2 -> Qo/Ko[r*1024+cl];
//         which==2 -> Vt[(b*1024+cl)*4096+s].
// MODE 3: QK scores. grid (32,32,4), z=batch. E = fp16 exp2(a2*s - 4*log2e),
//         row sums atomicAdd into Lsum[z*4096+row].  (alpha pre-scaled by
//         log2e so the epilogue is one v_fma + one v_exp per element.)
// ===========================================================================
template<int MODE>
__global__ __launch_bounds__(256)
void gemm128_kernel(const _Float16* __restrict__ A,
                    const _Float16* __restrict__ Bq,
                    const _Float16* __restrict__ Bk,
                    const _Float16* __restrict__ Bv,
                    const float* __restrict__ bq,
                    const float* __restrict__ bk,
                    const float* __restrict__ bv,
                    float alpha,
                    _Float16* __restrict__ Eo,
                    _Float16* __restrict__ Qo,
                    _Float16* __restrict__ Ko,
                    _Float16* __restrict__ Vo,
                    float* __restrict__ Lsum,
                    int K, int lda, int ldb) {
    __shared__ __align__(16) char smem[16384];
    char* sA = smem;          // 8 KB: 128 rows x 32 f16, swizzled 16B chunks
    char* sB = smem + 8192;

    const int tid  = threadIdx.x;
    const int lane = tid & 63;
    const int w    = tid >> 6;
    const int wm   = w & 1;
    const int wn   = w >> 1;
    const int quad = lane >> 4;
    const int l16  = lane & 15;
    const int swz  = (l16 >> 1) & 3;

    const int row0 = blockIdx.y * 128;
    const int col0 = blockIdx.x * 128;
    const int bz   = blockIdx.z;

    if (MODE == 3) {
        A    += (size_t)bz * SEQ * HIDDEN;
        Bq   += (size_t)bz * SEQ * HIDDEN;
        Eo   += (size_t)bz * SEQ * SEQ;
        Lsum += (size_t)bz * SEQ;
    }

    const _Float16* Bsrc = Bq;
    int colbase = col0;
    int which = 0;
    if (MODE == 5) {
        which = col0 >> 10;
        Bsrc = (which == 0) ? Bq : (which == 1) ? Bk : Bv;
        colbase = col0 & 1023;
    }

    floatx4 acc[4][4];
    #pragma unroll
    for (int i = 0; i < 4; ++i)
        #pragma unroll
        for (int j = 0; j < 4; ++j) acc[i][j] = (floatx4){0.f, 0.f, 0.f, 0.f};

    const f16x8* pA = (const f16x8*)sA;
    const f16x8* pB = (const f16x8*)sB;

    int srow[2], scol[2];
    #pragma unroll
    for (int it = 0; it < 2; ++it) {
        const int n = tid + it * 256;
        srow[it] = n >> 2;
        scol[it] = (n & 3) ^ ((srow[it] >> 1) & 3);
    }

    for (int k0 = 0; k0 < K; k0 += 32) {
        #pragma unroll
        for (int it = 0; it < 2; ++it) {
            const int n = tid + it * 256;
            const size_t ga = (size_t)(row0 + srow[it]) * lda + (size_t)k0 + scol[it] * 8;
            const size_t gb = (size_t)(colbase + srow[it]) * ldb + (size_t)k0 + scol[it] * 8;
            gld16(A + ga, sA + n * 16);
            gld16(Bsrc + gb, sB + n * 16);
        }
        __syncthreads();

        f16x8 af[4];
        #pragma unroll
        for (int i = 0; i < 4; ++i) {
            const int r = wm * 64 + i * 16 + l16;
            af[i] = pA[r * 4 + (quad ^ swz)];
        }
        #pragma unroll
        for (int j = 0; j < 4; ++j) {
            const int c = wn * 64 + j * 16 + l16;
            const f16x8 bf = pB[c * 4 + (quad ^ swz)];
            #pragma unroll
            for (int i = 0; i < 4; ++i)
                acc[i][j] = __builtin_amdgcn_mfma_f32_16x16x32_f16(af[i], bf, acc[i][j], 0, 0, 0);
        }
        __syncthreads();
    }

    // ---- epilogue (C/D layout: col=lane&15, row=quad*4+reg) ----
    #pragma unroll
    for (int i = 0; i < 4; ++i) {
        const int r0 = row0 + wm * 64 + i * 16 + quad * 4;
        float rp[4] = {0.f, 0.f, 0.f, 0.f};

        #pragma unroll
        for (int j = 0; j < 4; ++j) {
            const int cl = (MODE == 5 ? colbase : col0) + wn * 64 + j * 16 + l16;

            if (MODE == 5) {
                const float bcol = (which == 0 ? bq : which == 1 ? bk : bv)[cl];
                if (which < 2) {
                    _Float16* O = (which == 0) ? Qo : Ko;
                    #pragma unroll
                    for (int reg = 0; reg < 4; ++reg)
                        O[(size_t)(r0 + reg) * HIDDEN + cl] =
                            (_Float16)(acc[i][j][reg] + bcol);
                } else {
                    const int bb = r0 >> 12;
                    const int s  = r0 & 4095;
                    _Float16 t[4];
                    #pragma unroll
                    for (int reg = 0; reg < 4; ++reg)
                        t[reg] = (_Float16)(acc[i][j][reg] + bcol);
                    *(uint2*)&Vo[((size_t)bb * HIDDEN + cl) * SEQ + s] = *(const uint2*)t;
                }
            } else {  // MODE 3: alpha already includes log2e; exp2f -> v_exp_f32
                #pragma unroll
                for (int reg = 0; reg < 4; ++reg) {
                    const float v = exp2f(alpha * acc[i][j][reg] - 5.770780163555856f);
                    const _Float16 vh = (_Float16)v;
                    Eo[(size_t)(r0 + reg) * SEQ + cl] = vh;
                    rp[reg] += (float)vh;
                }
            }
        }

        if (MODE == 3) {
            #pragma unroll
            for (int off = 1; off < 16; off <<= 1)
                #pragma unroll
                for (int reg = 0; reg < 4; ++reg)
                    rp[reg] += __shfl_xor(rp[reg], off, 64);
            if (l16 == 0)
                #pragma unroll
                for (int reg = 0; reg < 4; ++reg)
                    atomicAdd(&Lsum[r0 + reg], rp[reg]);
        }
    }
}

// ===========================================================================
// 256x256-tile kernel, 512 thr = 8 waves (4x2), wave tile 64x128.
// MODE 4 (PV) only: LLC-demand-bound -> big tile halves E/Vt re-reads.
// grid (4,16,4). A=E (lda 4096), B=Vt[z] (ldb 4096). Cf = acc / Lsum[row].
// ===========================================================================
__global__ __launch_bounds__(512, 2)
void gemm256_pv_kernel(const _Float16* __restrict__ A,
                       const _Float16* __restrict__ B,
                       float* __restrict__ Cf,
                       const float* __restrict__ Lsum,
                       int K, int lda, int ldb) {
    __shared__ __align__(16) char smem[32768];
    char* sA = smem;
    char* sB = smem + 16384;

    const int tid  = threadIdx.x;
    const int lane = tid & 63;
    const int w    = tid >> 6;
    const int wr   = w & 3;
    const int wc   = w >> 2;
    const int quad = lane >> 4;
    const int l16  = lane & 15;
    const int swz  = (l16 >> 1) & 3;

    const int row0 = blockIdx.y * 256;
    const int col0 = blockIdx.x * 256;
    const int bz   = blockIdx.z;

    A    += (size_t)bz * SEQ * SEQ;
    B    += (size_t)bz * HIDDEN * SEQ;
    Cf   += (size_t)bz * SEQ * HIDDEN;
    Lsum += (size_t)bz * SEQ;

    floatx4 acc[4][8];
    #pragma unroll
    for (int i = 0; i < 4; ++i)
        #pragma unroll
        for (int j = 0; j < 8; ++j) acc[i][j] = (floatx4){0.f, 0.f, 0.f, 0.f};

    const f16x8* pA = (const f16x8*)sA;
    const f16x8* pB = (const f16x8*)sB;

    int srow[2], scol[2];
    #pragma unroll
    for (int it = 0; it < 2; ++it) {
        const int n = tid + it * 512;
        srow[it] = n >> 2;
        scol[it] = (n & 3) ^ ((srow[it] >> 1) & 3);
    }

    for (int k0 = 0; k0 < K; k0 += 32) {
        #pragma unroll
        for (int it = 0; it < 2; ++it) {
            const int n = tid + it * 512;
            const size_t ga = (size_t)(row0 + srow[it]) * lda + (size_t)k0 + scol[it] * 8;
            const size_t gb = (size_t)(col0 + srow[it]) * ldb + (size_t)k0 + scol[it] * 8;
            gld16(A + ga, sA + n * 16);
            gld16(B + gb, sB + n * 16);
        }
        __syncthreads();

        f16x8 af[4];
        #pragma unroll
        for (int i = 0; i < 4; ++i) {
            const int r = wr * 64 + i * 16 + l16;
            af[i] = pA[r * 4 + (quad ^ swz)];
        }
        #pragma unroll
        for (int j = 0; j < 8; ++j) {
            const int c = wc * 128 + j * 16 + l16;
            const f16x8 bf = pB[c * 4 + (quad ^ swz)];
            #pragma unroll
            for (int i = 0; i < 4; ++i)
                acc[i][j] = __builtin_amdgcn_mfma_f32_16x16x32_f16(af[i], bf, acc[i][j], 0, 0, 0);
        }
        __syncthreads();
    }

    #pragma unroll
    for (int i = 0; i < 4; ++i) {
        const int r0 = row0 + wr * 64 + i * 16 + quad * 4;
        float linv[4];
        #pragma unroll
        for (int reg = 0; reg < 4; ++reg) linv[reg] = 1.0f / Lsum[r0 + reg];
        #pragma unroll
        for (int j = 0; j < 8; ++j) {
            const int cl = col0 + wc * 128 + j * 16 + l16;
            #pragma unroll
            for (int reg = 0; reg < 4; ++reg)
                Cf[(size_t)(r0 + reg) * HIDDEN + cl] = acc[i][j][reg] * linv[reg];
        }
    }
}

// ---------------------------------------------------------------------------
// fp32 -> fp16 casts: X (grid.z==3 handled separately) and the 3 weights
// fused into one dispatch via blockIdx.z.
// ---------------------------------------------------------------------------
__global__ __launch_bounds__(256)
void cast_x_kernel(const float* __restrict__ in, _Float16* __restrict__ out) {
    const int i = blockIdx.x * 256 + threadIdx.x;
    const float4 x = ((const float4*)in)[i];
    _Float16 h[4] = {(_Float16)x.x, (_Float16)x.y, (_Float16)x.z, (_Float16)x.w};
    ((uint2*)out)[i] = *(const uint2*)h;
}

__global__ __launch_bounds__(256)
void cast_w_kernel(const float* __restrict__ w0, const float* __restrict__ w1,
                   const float* __restrict__ w2,
                   _Float16* __restrict__ o0, _Float16* __restrict__ o1,
                   _Float16* __restrict__ o2) {
    const float* in = (blockIdx.z == 0) ? w0 : (blockIdx.z == 1) ? w1 : w2;
    _Float16* out   = (blockIdx.z == 0) ? o0 : (blockIdx.z == 1) ? o1 : o2;
    const int i = blockIdx.x * 256 + threadIdx.x;
    const float4 x = ((const float4*)in)[i];
    _Float16 h[4] = {(_Float16)x.x, (_Float16)x.y, (_Float16)x.z, (_Float16)x.w};
    ((uint2*)out)[i] = *(const uint2*)h;
}

// ---------------------------------------------------------------------------
// ws layout (bytes), total ~235 MB:
//   [0, 134.2M) : E fp16 [B][S][S]  (head aliases Xh + W casts, dead by then)
//   then        : Qh 33.5M | Kh 33.5M | Vt [B][H][S] 33.5M | Lsum 64K
// ---------------------------------------------------------------------------
extern "C" void kernel_launch(void* const* d_in, const int* in_sizes, int n_in,
                              void* d_out, int out_size, void* d_ws, size_t ws_size,
                              hipStream_t stream) {
    const float* X  = (const float*)d_in[0];
    const float* Wq = (const float*)d_in[1];
    const float* bq = (const float*)d_in[2];
    const float* Wk = (const float*)d_in[3];
    const float* bk = (const float*)d_in[4];
    const float* Wv = (const float*)d_in[5];
    const float* bv = (const float*)d_in[6];
    float* out = (float*)d_out;

    char* ws = (char*)d_ws;
    const size_t EB = (size_t)BATCH * SEQ * SEQ * 2;     // 134,217,728
    const size_t XB = (size_t)BATCH * SEQ * HIDDEN * 2;  // 33,554,432
    const size_t WB = (size_t)HIDDEN * HIDDEN * 2;       // 2,097,152

    _Float16* E   = (_Float16*)ws;
    _Float16* Xh  = (_Float16*)ws;                       // aliases E head
    _Float16* Wqh = (_Float16*)(ws + XB);
    _Float16* Wkh = (_Float16*)(ws + XB + WB);
    _Float16* Wvh = (_Float16*)(ws + XB + 2 * WB);
    _Float16* Qh  = (_Float16*)(ws + EB);
    _Float16* Kh  = (_Float16*)(ws + EB + XB);
    _Float16* Vt  = (_Float16*)(ws + EB + 2 * XB);       // [B][H][S]
    float*    Lsum= (float*)   (ws + EB + 3 * XB);       // [B][S]

    // 1. casts
    cast_x_kernel<<<dim3(16384), dim3(256), 0, stream>>>(X, Xh);
    cast_w_kernel<<<dim3(1024, 1, 3), dim3(256), 0, stream>>>(
        Wq, Wk, Wv, Wqh, Wkh, Wvh);

    hipMemsetAsync(Lsum, 0, (size_t)BATCH * SEQ * sizeof(float), stream);

    // 2. fused QKV projection: [16384,1024] x [3072,1024]^T, 128^2 tiles
    gemm128_kernel<5><<<dim3(24, 128, 1), dim3(256), 0, stream>>>(
        Xh, Wqh, Wkh, Wvh, bq, bk, bv, 1.0f,
        nullptr, Qh, Kh, Vt, nullptr,
        HIDDEN, HIDDEN, HIDDEN);

    // 3. QK^T -> exp -> E (fp16) + row sums, 128^2 tiles (occupancy-bound)
    const float alpha2 = (1.0f / 32.0f) * 1.4426950408889634f;  // /sqrt(H) * log2e
    gemm128_kernel<3><<<dim3(32, 32, 4), dim3(256), 0, stream>>>(
        Qh, Kh, nullptr, nullptr, nullptr, nullptr, nullptr, alpha2,
        E, nullptr, nullptr, nullptr, Lsum,
        HIDDEN, HIDDEN, HIDDEN);

    // 4. PV with 1/Lsum scaling, 256^2 tiles (LLC-demand-bound)
    gemm256_pv_kernel<<<dim3(4, 16, 4), dim3(512), 0, stream>>>(
        E, Vt, out, Lsum, SEQ, SEQ, SEQ);
}

// Round 7
// 625.251 us; speedup vs baseline: 1.0905x; 1.0905x over previous
//
#include <hip/hip_runtime.h>
#include <math.h>

#define HIDDEN 1024
#define SEQ    4096
#define BATCH  4

typedef _Float16 f16x8 __attribute__((ext_vector_type(8)));
typedef float    floatx4 __attribute__((ext_vector_type(4)));

// async 16B global->LDS copy (m97: width=16 emits global_load_lds_dwordx4)
__device__ inline void gld16(const void* g, void* l) {
    __builtin_amdgcn_global_load_lds(
        (const __attribute__((address_space(1))) unsigned int*)g,
        (__attribute__((address_space(3))) unsigned int*)l, 16, 0, 0);
}

// ===========================================================================
// 128x128-tile kernel, 256 thr = 4 waves (2x2), wave tile 64x64.
// MODE 5: fused QKV projection. grid (24,128,1). A=Xh [16384,1024].
//         XCD swizzle: the 24 col-tiles of one X row-strip map to ONE XCD
//         (adjacent slots) so the shared A-tile front is an L2 hit.
//         which = col0>>10 picks Wq/Wk/Wv; which<2 -> Qo/Ko[r*1024+cl];
//         which==2 -> Vt[(b*1024+cl)*4096+s].
// MODE 3: QK scores. grid (32,32,4), z=batch. E = fp16 exp2(a2*s - 4*log2e),
//         row sums atomicAdd into Lsum[z*4096+row].
// ===========================================================================
template<int MODE>
__global__ __launch_bounds__(256)
void gemm128_kernel(const _Float16* __restrict__ A,
                    const _Float16* __restrict__ Bq,
                    const _Float16* __restrict__ Bk,
                    const _Float16* __restrict__ Bv,
                    const float* __restrict__ bq,
                    const float* __restrict__ bk,
                    const float* __restrict__ bv,
                    float alpha,
                    _Float16* __restrict__ Eo,
                    _Float16* __restrict__ Qo,
                    _Float16* __restrict__ Ko,
                    _Float16* __restrict__ Vo,
                    float* __restrict__ Lsum,
                    int K, int lda, int ldb) {
    __shared__ __align__(16) char smem[16384];
    char* sA = smem;          // 8 KB: 128 rows x 32 f16, swizzled 16B chunks
    char* sB = smem + 8192;

    const int tid  = threadIdx.x;
    const int lane = tid & 63;
    const int w    = tid >> 6;
    const int wm   = w & 1;
    const int wn   = w >> 1;
    const int quad = lane >> 4;
    const int l16  = lane & 15;
    const int swz  = (l16 >> 1) & 3;

    int row0, col0;
    if (MODE == 5) {
        // XCD swizzle: n%8 = XCD (round-robin dispatch assumption).
        const int n    = blockIdx.x + 24 * blockIdx.y;
        const int xcd  = n & 7;
        const int slot = n >> 3;                 // 0..383
        const int cc   = slot % 24;
        const int rg   = xcd + 8 * (slot / 24);  // 0..127
        row0 = rg * 128;
        col0 = cc * 128;
    } else {
        row0 = blockIdx.y * 128;
        col0 = blockIdx.x * 128;
    }
    const int bz = blockIdx.z;

    if (MODE == 3) {
        A    += (size_t)bz * SEQ * HIDDEN;
        Bq   += (size_t)bz * SEQ * HIDDEN;
        Eo   += (size_t)bz * SEQ * SEQ;
        Lsum += (size_t)bz * SEQ;
    }

    const _Float16* Bsrc = Bq;
    int colbase = col0;
    int which = 0;
    if (MODE == 5) {
        which = col0 >> 10;
        Bsrc = (which == 0) ? Bq : (which == 1) ? Bk : Bv;
        colbase = col0 & 1023;
    }

    floatx4 acc[4][4];
    #pragma unroll
    for (int i = 0; i < 4; ++i)
        #pragma unroll
        for (int j = 0; j < 4; ++j) acc[i][j] = (floatx4){0.f, 0.f, 0.f, 0.f};

    const f16x8* pA = (const f16x8*)sA;
    const f16x8* pB = (const f16x8*)sB;

    int srow[2], scol[2];
    #pragma unroll
    for (int it = 0; it < 2; ++it) {
        const int n = tid + it * 256;
        srow[it] = n >> 2;
        scol[it] = (n & 3) ^ ((srow[it] >> 1) & 3);
    }

    for (int k0 = 0; k0 < K; k0 += 32) {
        #pragma unroll
        for (int it = 0; it < 2; ++it) {
            const int n = tid + it * 256;
            const size_t ga = (size_t)(row0 + srow[it]) * lda + (size_t)k0 + scol[it] * 8;
            const size_t gb = (size_t)(colbase + srow[it]) * ldb + (size_t)k0 + scol[it] * 8;
            gld16(A + ga, sA + n * 16);
            gld16(Bsrc + gb, sB + n * 16);
        }
        __syncthreads();

        f16x8 af[4];
        #pragma unroll
        for (int i = 0; i < 4; ++i) {
            const int r = wm * 64 + i * 16 + l16;
            af[i] = pA[r * 4 + (quad ^ swz)];
        }
        #pragma unroll
        for (int j = 0; j < 4; ++j) {
            const int c = wn * 64 + j * 16 + l16;
            const f16x8 bf = pB[c * 4 + (quad ^ swz)];
            #pragma unroll
            for (int i = 0; i < 4; ++i)
                acc[i][j] = __builtin_amdgcn_mfma_f32_16x16x32_f16(af[i], bf, acc[i][j], 0, 0, 0);
        }
        __syncthreads();
    }

    // ---- epilogue (C/D layout: col=lane&15, row=quad*4+reg) ----
    #pragma unroll
    for (int i = 0; i < 4; ++i) {
        const int r0 = row0 + wm * 64 + i * 16 + quad * 4;
        float rp[4] = {0.f, 0.f, 0.f, 0.f};

        #pragma unroll
        for (int j = 0; j < 4; ++j) {
            const int cl = (MODE == 5 ? colbase : col0) + wn * 64 + j * 16 + l16;

            if (MODE == 5) {
                const float bcol = (which == 0 ? bq : which == 1 ? bk : bv)[cl];
                if (which < 2) {
                    _Float16* O = (which == 0) ? Qo : Ko;
                    #pragma unroll
                    for (int reg = 0; reg < 4; ++reg)
                        O[(size_t)(r0 + reg) * HIDDEN + cl] =
                            (_Float16)(acc[i][j][reg] + bcol);
                } else {
                    const int bb = r0 >> 12;
                    const int s  = r0 & 4095;
                    _Float16 t[4];
                    #pragma unroll
                    for (int reg = 0; reg < 4; ++reg)
                        t[reg] = (_Float16)(acc[i][j][reg] + bcol);
                    *(uint2*)&Vo[((size_t)bb * HIDDEN + cl) * SEQ + s] = *(const uint2*)t;
                }
            } else {  // MODE 3: alpha includes log2e; exp2f -> v_exp_f32
                #pragma unroll
                for (int reg = 0; reg < 4; ++reg) {
                    const float v = exp2f(alpha * acc[i][j][reg] - 5.770780163555856f);
                    const _Float16 vh = (_Float16)v;
                    Eo[(size_t)(r0 + reg) * SEQ + cl] = vh;
                    rp[reg] += (float)vh;
                }
            }
        }

        if (MODE == 3) {
            #pragma unroll
            for (int off = 1; off < 16; off <<= 1)
                #pragma unroll
                for (int reg = 0; reg < 4; ++reg)
                    rp[reg] += __shfl_xor(rp[reg], off, 64);
            if (l16 == 0)
                #pragma unroll
                for (int reg = 0; reg < 4; ++reg)
                    atomicAdd(&Lsum[r0 + reg], rp[reg]);
        }
    }
}

// ===========================================================================
// PV kernel: 128x256 tile, 256 thr = 4 waves (2x2), wave tile 64x128.
// ~180 regs -> 2 blocks/CU (barrier-drain overlap). grid = 512 linear blocks.
// XCD swizzle: the 4 col-tile blocks sharing one E row-strip land on ONE XCD
// with adjacent slots -> shared A-tile K-loop front is an L2 hit (E re-reads
// stop going to HBM). A=E[b] (lda 4096), B=Vt[b] (ldb 4096).
// Cf[r*1024+c] = acc / Lsum[row].
// ===========================================================================
__global__ __launch_bounds__(256, 2)
void gemm_pv_kernel(const _Float16* __restrict__ A,
                    const _Float16* __restrict__ B,
                    float* __restrict__ Cf,
                    const float* __restrict__ Lsum) {
    __shared__ __align__(16) char smem[24576];
    char* sA = smem;            //  8 KB: 128 rows x 32 f16
    char* sB = smem + 8192;     // 16 KB: 256 rows x 32 f16

    const int tid  = threadIdx.x;
    const int lane = tid & 63;
    const int w    = tid >> 6;
    const int wm   = w & 1;           // 64-row half
    const int wn   = w >> 1;          // 128-col half
    const int quad = lane >> 4;
    const int l16  = lane & 15;
    const int swz  = (l16 >> 1) & 3;

    // swizzled decomposition: n%8 = XCD; c fastest within XCD slot group
    const int n    = blockIdx.x;          // 0..511
    const int xcd  = n & 7;
    const int slot = n >> 3;              // 0..63
    const int c    = slot & 3;            // col tile 0..3
    const int rg   = xcd + 8 * (slot >> 2);  // 0..127
    const int r    = rg & 31;             // row tile within batch
    const int bz   = rg >> 5;             // batch

    const int row0 = r * 128;
    const int col0 = c * 256;

    A    += (size_t)bz * SEQ * SEQ;
    B    += (size_t)bz * HIDDEN * SEQ;
    Cf   += (size_t)bz * SEQ * HIDDEN;
    Lsum += (size_t)bz * SEQ;

    floatx4 acc[4][8];
    #pragma unroll
    for (int i = 0; i < 4; ++i)
        #pragma unroll
        for (int j = 0; j < 8; ++j) acc[i][j] = (floatx4){0.f, 0.f, 0.f, 0.f};

    const f16x8* pA = (const f16x8*)sA;
    const f16x8* pB = (const f16x8*)sB;

    for (int k0 = 0; k0 < SEQ; k0 += 32) {
        // A: 512 chunks (2/thread); B: 1024 chunks (4/thread)
        #pragma unroll
        for (int it = 0; it < 2; ++it) {
            const int nc = tid + it * 256;
            const int sr = nc >> 2;
            const int sc = (nc & 3) ^ ((sr >> 1) & 3);
            gld16(A + (size_t)(row0 + sr) * SEQ + k0 + sc * 8, sA + nc * 16);
        }
        #pragma unroll
        for (int it = 0; it < 4; ++it) {
            const int nc = tid + it * 256;
            const int sr = nc >> 2;
            const int sc = (nc & 3) ^ ((sr >> 1) & 3);
            gld16(B + (size_t)(col0 + sr) * SEQ + k0 + sc * 8, sB + nc * 16);
        }
        __syncthreads();

        f16x8 af[4];
        #pragma unroll
        for (int i = 0; i < 4; ++i) {
            const int rr = wm * 64 + i * 16 + l16;
            af[i] = pA[rr * 4 + (quad ^ swz)];
        }
        #pragma unroll
        for (int j = 0; j < 8; ++j) {
            const int cc = wn * 128 + j * 16 + l16;
            const f16x8 bf = pB[cc * 4 + (quad ^ swz)];
            #pragma unroll
            for (int i = 0; i < 4; ++i)
                acc[i][j] = __builtin_amdgcn_mfma_f32_16x16x32_f16(af[i], bf, acc[i][j], 0, 0, 0);
        }
        __syncthreads();
    }

    #pragma unroll
    for (int i = 0; i < 4; ++i) {
        const int r0 = row0 + wm * 64 + i * 16 + quad * 4;
        float linv[4];
        #pragma unroll
        for (int reg = 0; reg < 4; ++reg) linv[reg] = 1.0f / Lsum[r0 + reg];
        #pragma unroll
        for (int j = 0; j < 8; ++j) {
            const int cl = col0 + wn * 128 + j * 16 + l16;
            #pragma unroll
            for (int reg = 0; reg < 4; ++reg)
                Cf[(size_t)(r0 + reg) * HIDDEN + cl] = acc[i][j][reg] * linv[reg];
        }
    }
}

// ---------------------------------------------------------------------------
// fp32 -> fp16 casts
// ---------------------------------------------------------------------------
__global__ __launch_bounds__(256)
void cast_x_kernel(const float* __restrict__ in, _Float16* __restrict__ out) {
    const int i = blockIdx.x * 256 + threadIdx.x;
    const float4 x = ((const float4*)in)[i];
    _Float16 h[4] = {(_Float16)x.x, (_Float16)x.y, (_Float16)x.z, (_Float16)x.w};
    ((uint2*)out)[i] = *(const uint2*)h;
}

__global__ __launch_bounds__(256)
void cast_w_kernel(const float* __restrict__ w0, const float* __restrict__ w1,
                   const float* __restrict__ w2,
                   _Float16* __restrict__ o0, _Float16* __restrict__ o1,
                   _Float16* __restrict__ o2) {
    const float* in = (blockIdx.z == 0) ? w0 : (blockIdx.z == 1) ? w1 : w2;
    _Float16* out   = (blockIdx.z == 0) ? o0 : (blockIdx.z == 1) ? o1 : o2;
    const int i = blockIdx.x * 256 + threadIdx.x;
    const float4 x = ((const float4*)in)[i];
    _Float16 h[4] = {(_Float16)x.x, (_Float16)x.y, (_Float16)x.z, (_Float16)x.w};
    ((uint2*)out)[i] = *(const uint2*)h;
}

// ---------------------------------------------------------------------------
// ws layout (bytes), total ~235 MB:
//   [0, 134.2M) : E fp16 [B][S][S]  (head aliases Xh + W casts, dead by then)
//   then        : Qh 33.5M | Kh 33.5M | Vt [B][H][S] 33.5M | Lsum 64K
// ---------------------------------------------------------------------------
extern "C" void kernel_launch(void* const* d_in, const int* in_sizes, int n_in,
                              void* d_out, int out_size, void* d_ws, size_t ws_size,
                              hipStream_t stream) {
    const float* X  = (const float*)d_in[0];
    const float* Wq = (const float*)d_in[1];
    const float* bq = (const float*)d_in[2];
    const float* Wk = (const float*)d_in[3];
    const float* bk = (const float*)d_in[4];
    const float* Wv = (const float*)d_in[5];
    const float* bv = (const float*)d_in[6];
    float* out = (float*)d_out;

    char* ws = (char*)d_ws;
    const size_t EB = (size_t)BATCH * SEQ * SEQ * 2;     // 134,217,728
    const size_t XB = (size_t)BATCH * SEQ * HIDDEN * 2;  // 33,554,432
    const size_t WB = (size_t)HIDDEN * HIDDEN * 2;       // 2,097,152

    _Float16* E   = (_Float16*)ws;
    _Float16* Xh  = (_Float16*)ws;                       // aliases E head
    _Float16* Wqh = (_Float16*)(ws + XB);
    _Float16* Wkh = (_Float16*)(ws + XB + WB);
    _Float16* Wvh = (_Float16*)(ws + XB + 2 * WB);
    _Float16* Qh  = (_Float16*)(ws + EB);
    _Float16* Kh  = (_Float16*)(ws + EB + XB);
    _Float16* Vt  = (_Float16*)(ws + EB + 2 * XB);       // [B][H][S]
    float*    Lsum= (float*)   (ws + EB + 3 * XB);       // [B][S]

    // 1. casts
    cast_x_kernel<<<dim3(16384), dim3(256), 0, stream>>>(X, Xh);
    cast_w_kernel<<<dim3(1024, 1, 3), dim3(256), 0, stream>>>(
        Wq, Wk, Wv, Wqh, Wkh, Wvh);

    hipMemsetAsync(Lsum, 0, (size_t)BATCH * SEQ * sizeof(float), stream);

    // 2. fused QKV projection: [16384,1024] x [3072,1024]^T, 128^2 tiles
    gemm128_kernel<5><<<dim3(24, 128, 1), dim3(256), 0, stream>>>(
        Xh, Wqh, Wkh, Wvh, bq, bk, bv, 1.0f,
        nullptr, Qh, Kh, Vt, nullptr,
        HIDDEN, HIDDEN, HIDDEN);

    // 3. QK^T -> exp -> E (fp16) + row sums, 128^2 tiles
    const float alpha2 = (1.0f / 32.0f) * 1.4426950408889634f;  // /sqrt(H)*log2e
    gemm128_kernel<3><<<dim3(32, 32, 4), dim3(256), 0, stream>>>(
        Qh, Kh, nullptr, nullptr, nullptr, nullptr, nullptr, alpha2,
        E, nullptr, nullptr, nullptr, Lsum,
        HIDDEN, HIDDEN, HIDDEN);

    // 4. PV with 1/Lsum scaling, 128x256 tiles + XCD swizzle
    gemm_pv_kernel<<<dim3(512), dim3(256), 0, stream>>>(E, Vt, out, Lsum);
}